// Round 12
// baseline (120.429 us; speedup 1.0000x reference)
//
#include <hip/hip_runtime.h>
#include <stdint.h>

#define S_LEN 2048
#define NB 2
#define NH 16
#define DK 64
#define DM 1024
#define QK_SCALE 0.125f
#define NEG_BIG -1e30f

typedef __attribute__((ext_vector_type(8))) short bf16x8;
typedef __attribute__((ext_vector_type(4))) float f32x4;

static __device__ __forceinline__ f32x4 mfma16(bf16x8 a, bf16x8 b, f32x4 c) {
    return __builtin_amdgcn_mfma_f32_16x16x32_bf16(a, b, c, 0, 0, 0);
}

// async global->LDS, 16B per lane; dst is wave-uniform base, HW adds lane*16
static __device__ __forceinline__ void gload_lds16(const void* g, void* l) {
    __builtin_amdgcn_global_load_lds((const __attribute__((address_space(1))) void*)g,
                                     (__attribute__((address_space(3))) void*)l,
                                     16, 0, 0);
}

// fp32 -> bf16 bits, RNE (inputs always finite here)
static __device__ __forceinline__ unsigned short f2bf(float x) {
    unsigned int u = __float_as_uint(x);
    u += 0x7fffu + ((u >> 16) & 1u);
    return (unsigned short)(u >> 16);
}

// ---------------- conversion: fp32 -> bf16, 7 tensors in one launch -------
struct CvtArgs {
    const float* src[7];
    unsigned short* dst[7];
    int n8[7];
};

__global__ __launch_bounds__(256) void cvt_f32_bf16(CvtArgs a) {
    const int t = blockIdx.y;
    const float* __restrict__ src = a.src[t];
    unsigned short* __restrict__ dst = a.dst[t];
    const int n8 = a.n8[t];
    const int stride = gridDim.x * blockDim.x;
    for (int i = blockIdx.x * blockDim.x + threadIdx.x; i < n8; i += stride) {
        float4 v0 = ((const float4*)src)[(size_t)i * 2];
        float4 v1 = ((const float4*)src)[(size_t)i * 2 + 1];
        union { bf16x8 v; unsigned short h[8]; } u;
        u.h[0] = f2bf(v0.x); u.h[1] = f2bf(v0.y); u.h[2] = f2bf(v0.z); u.h[3] = f2bf(v0.w);
        u.h[4] = f2bf(v1.x); u.h[5] = f2bf(v1.y); u.h[6] = f2bf(v1.z); u.h[7] = f2bf(v1.w);
        ((bf16x8*)dst)[i] = u.v;
    }
}

// ---------------- GEMM core: C[128x128] = A[M,K] * W[N,K]^T ----------------
// m97-structure: 128^2 tile, BK=64, global_load_lds(16B), 2 barriers/K-step,
// T2 swizzle (r7, PMC-verified conflict-free: 9.4M -> 0). r9 known-good form.
static __device__ __forceinline__ void gemm_core_128(
    const unsigned short* __restrict__ A,
    const unsigned short* __restrict__ W,
    unsigned short* sA, unsigned short* sB,
    int K, int m0, int n0, f32x4 acc[4][4])
{
    const int tid = threadIdx.x;
    const int wid = tid >> 6, lane = tid & 63;
    const int wr = wid >> 1, wc = wid & 1;
    const int fr = lane & 15, fg = lane >> 4;
    const int ldr = lane >> 3;
    const int ldc = ((lane & 7) ^ (lane >> 3)) * 8;   // pre-swizzled global src

    const unsigned short* pA = A + (size_t)(m0 + ldr) * K + ldc;
    const unsigned short* pW = W + (size_t)(n0 + ldr) * K + ldc;

    const int cka0 = ((0 + fg) ^ (fr & 7)) * 8;   // swizzled frag-read offsets
    const int cka1 = ((4 + fg) ^ (fr & 7)) * 8;

    for (int k0 = 0; k0 < K; k0 += 64) {
        __syncthreads();  // previous compute done reading LDS
        #pragma unroll
        for (int it = 0; it < 4; ++it) {
            const int rb = wid * 32 + it * 8;
            gload_lds16(pA + (size_t)(rb)*K + k0, sA + rb * 64);
            gload_lds16(pW + (size_t)(rb)*K + k0, sB + rb * 64);
        }
        __syncthreads();  // implies s_waitcnt vmcnt(0): staged data visible
        #pragma unroll
        for (int kf = 0; kf < 2; ++kf) {
            const int cka = kf ? cka1 : cka0;
            bf16x8 af[4], bfr[4];
            #pragma unroll
            for (int mf = 0; mf < 4; ++mf)
                af[mf] = *(const bf16x8*)(sA + (wr * 64 + mf * 16 + fr) * 64 + cka);
            #pragma unroll
            for (int nf = 0; nf < 4; ++nf)
                bfr[nf] = *(const bf16x8*)(sB + (wc * 64 + nf * 16 + fr) * 64 + cka);
            #pragma unroll
            for (int mf = 0; mf < 4; ++mf)
                #pragma unroll
                for (int nf = 0; nf < 4; ++nf)
                    acc[mf][nf] = mfma16(af[mf], bfr[nf], acc[mf][nf]);
        }
    }
}

// ---------------- merged QKV projection (grid.z selects Q/K/V) -------------
// z=0: Q*SCALE -> [B,H,S,dk]  (QK_SCALE=2^-3 folded: bit-exact exponent shift);
// z=1: K -> [B,H,S,dk]; z=2: V -> [B,H,dk,S] (transposed). r9 known-good form.
__global__ __launch_bounds__(256, 3) void gemm_qkv(
    const unsigned short* __restrict__ Xq, const unsigned short* __restrict__ Xk,
    const unsigned short* __restrict__ Xv,
    const unsigned short* __restrict__ Wq, const unsigned short* __restrict__ Wk,
    const unsigned short* __restrict__ Wv,
    const float* __restrict__ bq, const float* __restrict__ bk, const float* __restrict__ bv,
    unsigned short* __restrict__ Qo, unsigned short* __restrict__ Ko,
    unsigned short* __restrict__ Vt)
{
    __shared__ unsigned short sA[128 * 64];
    __shared__ unsigned short sB[128 * 64];
    const int z = blockIdx.z;
    const unsigned short* A = (z == 0) ? Xq : ((z == 1) ? Xk : Xv);
    const unsigned short* W = (z == 0) ? Wq : ((z == 1) ? Wk : Wv);
    const float* bias = (z == 0) ? bq : ((z == 1) ? bk : bv);
    const int m0 = blockIdx.y * 128, n0 = blockIdx.x * 128;

    f32x4 acc[4][4] = {};
    gemm_core_128(A, W, sA, sB, DM, m0, n0, acc);

    const int tid = threadIdx.x, wid = tid >> 6, lane = tid & 63;
    const int wr = wid >> 1, wc = wid & 1, fr = lane & 15, fg = lane >> 4;
    const float sc = (z == 0) ? QK_SCALE : 1.0f;   // fold scale into Q
    unsigned short* Oh = (z == 0) ? Qo : Ko;
    #pragma unroll
    for (int nf = 0; nf < 4; ++nf) {
        const int col = n0 + wc * 64 + nf * 16 + fr;
        const float bb = bias[col];
        const int h = col >> 6, dd = col & (DK - 1);
        #pragma unroll
        for (int mf = 0; mf < 4; ++mf) {
            #pragma unroll
            for (int r = 0; r < 4; ++r) {
                const int row = m0 + wr * 64 + mf * 16 + fg * 4 + r;
                const int b = row >> 11, s = row & (S_LEN - 1);
                const float val = (acc[mf][nf][r] + bb) * sc;
                if (z < 2)
                    Oh[(((size_t)b * NH + h) * S_LEN + s) * DK + dd] = f2bf(val);
                else
                    Vt[(((size_t)b * NH + h) * DK + dd) * S_LEN + s] = f2bf(val);
            }
        }
    }
}

// ---------------- final output projection: BM=64 tile, fp32 out + bias -----
__global__ __launch_bounds__(256, 3) void gemm_out(
    const unsigned short* __restrict__ A, const unsigned short* __restrict__ W,
    const float* __restrict__ bias, float* __restrict__ out)
{
    __shared__ unsigned short sA[64 * 64];
    __shared__ unsigned short sB[128 * 64];

    const int tid = threadIdx.x;
    const int wid = tid >> 6, lane = tid & 63;
    const int wr = wid >> 1, wc = wid & 1;
    const int fr = lane & 15, fg = lane >> 4;
    const int ldr = lane >> 3;
    const int ldc = ((lane & 7) ^ (lane >> 3)) * 8;
    const int m0 = blockIdx.y * 64, n0 = blockIdx.x * 128;

    const unsigned short* pA = A + (size_t)(m0 + ldr) * DM + ldc;
    const unsigned short* pW = W + (size_t)(n0 + ldr) * DM + ldc;

    const int cka0 = ((0 + fg) ^ (fr & 7)) * 8;
    const int cka1 = ((4 + fg) ^ (fr & 7)) * 8;

    f32x4 acc[2][4] = {};

    for (int k0 = 0; k0 < DM; k0 += 64) {
        __syncthreads();
        #pragma unroll
        for (int it = 0; it < 2; ++it) {
            const int rb = wid * 16 + it * 8;
            gload_lds16(pA + (size_t)rb * DM + k0, sA + rb * 64);
        }
        #pragma unroll
        for (int it = 0; it < 4; ++it) {
            const int rb = wid * 32 + it * 8;
            gload_lds16(pW + (size_t)rb * DM + k0, sB + rb * 64);
        }
        __syncthreads();
        #pragma unroll
        for (int kf = 0; kf < 2; ++kf) {
            const int cka = kf ? cka1 : cka0;
            bf16x8 af[2], bfr[4];
            #pragma unroll
            for (int mf = 0; mf < 2; ++mf)
                af[mf] = *(const bf16x8*)(sA + (wr * 32 + mf * 16 + fr) * 64 + cka);
            #pragma unroll
            for (int nf = 0; nf < 4; ++nf)
                bfr[nf] = *(const bf16x8*)(sB + (wc * 64 + nf * 16 + fr) * 64 + cka);
            #pragma unroll
            for (int mf = 0; mf < 2; ++mf)
                #pragma unroll
                for (int nf = 0; nf < 4; ++nf)
                    acc[mf][nf] = mfma16(af[mf], bfr[nf], acc[mf][nf]);
        }
    }

    #pragma unroll
    for (int nf = 0; nf < 4; ++nf) {
        const int col = n0 + wc * 64 + nf * 16 + fr;
        const float bb = bias[col];
        #pragma unroll
        for (int mf = 0; mf < 2; ++mf) {
            #pragma unroll
            for (int r = 0; r < 4; ++r) {
                const int row = m0 + wr * 32 + mf * 16 + fg * 4 + r;
                out[(size_t)row * DM + col] = acc[mf][nf][r] + bb;
            }
        }
    }
}

// ---------------- banded flash attention, NO K/V staging -------------------
// K/V are L2/L3-warm (just written by gemm_qkv; 16MB total). Fragments are
// read DIRECTLY from global (16B-contiguous), like Q already was — removing
// the LDS bounce, both barriers, and the vmcnt(0) drain per tile. sP remains
// (per-wave private; same-wave RAW via lgkmcnt) -> kernel is barrier-free.
__global__ __launch_bounds__(256, 3) void attn_kernel(
    const unsigned short* __restrict__ Qb,   // [B,H,S,64], pre-scaled
    const unsigned short* __restrict__ Kb,   // [B,H,S,64]
    const unsigned short* __restrict__ Vt,   // [B,H,64,S]
    unsigned short* __restrict__ Oout)       // [B*S, 1024] token-major
{
    __shared__ unsigned short sP[4][32 * 128];

    const int tid = threadIdx.x, wid = tid >> 6, lane = tid & 63;
    const int fr = lane & 15, fg = lane >> 4;
    const int qt = blockIdx.x, bh = blockIdx.y;
    const int q0 = qt * 128;
    const size_t base = (size_t)bh * (S_LEN * DK);

    bf16x8 qf[2][2];
    #pragma unroll
    for (int mf = 0; mf < 2; ++mf)
        #pragma unroll
        for (int kf = 0; kf < 2; ++kf)
            qf[mf][kf] = *(const bf16x8*)(Qb + base +
                (size_t)(q0 + wid * 32 + mf * 16 + fr) * DK + kf * 32 + fg * 8);

    f32x4 oacc[2][4] = {};
    float m_run[2][4], l_run[2][4];
    #pragma unroll
    for (int mf = 0; mf < 2; ++mf)
        #pragma unroll
        for (int r = 0; r < 4; ++r) { m_run[mf][r] = NEG_BIG; l_run[mf][r] = 0.f; }

    const int t_lo = (qt == 0) ? 1 : 0;
    const int t_hi = (qt == (S_LEN / 128 - 1)) ? 1 : 2;

    for (int t = t_lo; t <= t_hi; ++t) {
        const int kt0 = q0 + (t - 1) * 128;

        // S = Q K^T, K fragments straight from global (L2-warm)
        f32x4 sacc[2][8] = {};
        #pragma unroll
        for (int kf = 0; kf < 2; ++kf) {
            bf16x8 kfr[8];
            #pragma unroll
            for (int nf = 0; nf < 8; ++nf)
                kfr[nf] = *(const bf16x8*)(Kb + base +
                    (size_t)(kt0 + nf * 16 + fr) * DK + kf * 32 + fg * 8);
            #pragma unroll
            for (int mf = 0; mf < 2; ++mf)
                #pragma unroll
                for (int nf = 0; nf < 8; ++nf)
                    sacc[mf][nf] = mfma16(qf[mf][kf], kfr[nf], sacc[mf][nf]);
        }

        const int dt = (t - 1) * 128;
        #pragma unroll
        for (int mf = 0; mf < 2; ++mf) {
            #pragma unroll
            for (int r = 0; r < 4; ++r) {
                const int row = wid * 32 + mf * 16 + fg * 4 + r;
                float mm = NEG_BIG;
                #pragma unroll
                for (int nf = 0; nf < 8; ++nf) {
                    const int col = nf * 16 + fr;
                    const int diff = dt + col - row;   // j - i
                    float s = sacc[mf][nf][r];         // pre-scaled via Q
                    s = (diff >= -128 && diff < 128) ? s : NEG_BIG;
                    sacc[mf][nf][r] = s;
                    mm = fmaxf(mm, s);
                }
                #pragma unroll
                for (int d = 1; d < 16; d <<= 1) mm = fmaxf(mm, __shfl_xor(mm, d));
                const float mold = m_run[mf][r];
                const float mn = fmaxf(mold, mm);
                m_run[mf][r] = mn;
                const float alpha = __expf(mold - mn);
                float ps = 0.f;
                #pragma unroll
                for (int nf = 0; nf < 8; ++nf) {
                    const float p = __expf(sacc[mf][nf][r] - mn);
                    ps += p;
                    sP[wid][(mf * 16 + fg * 4 + r) * 128 + nf * 16 + fr] = f2bf(p);
                }
                #pragma unroll
                for (int d = 1; d < 16; d <<= 1) ps += __shfl_xor(ps, d);
                l_run[mf][r] = l_run[mf][r] * alpha + ps;
                #pragma unroll
                for (int nf = 0; nf < 4; ++nf)
                    oacc[mf][nf][r] = oacc[mf][nf][r] * alpha;
            }
        }

        // O += P @ V, V fragments straight from global (Vt is [d][S])
        #pragma unroll
        for (int kf = 0; kf < 4; ++kf) {
            bf16x8 pa[2], vb[4];
            #pragma unroll
            for (int mf = 0; mf < 2; ++mf)
                pa[mf] = *(const bf16x8*)(&sP[wid][(mf * 16 + fr) * 128 + kf * 32 + fg * 8]);
            #pragma unroll
            for (int nf = 0; nf < 4; ++nf)
                vb[nf] = *(const bf16x8*)(Vt + base +
                    (size_t)(nf * 16 + fr) * S_LEN + kt0 + kf * 32 + fg * 8);
            #pragma unroll
            for (int mf = 0; mf < 2; ++mf)
                #pragma unroll
                for (int nf = 0; nf < 4; ++nf)
                    oacc[mf][nf] = mfma16(pa[mf], vb[nf], oacc[mf][nf]);
        }
    }

    const int b = bh >> 4, h = bh & 15;
    #pragma unroll
    for (int mf = 0; mf < 2; ++mf) {
        #pragma unroll
        for (int r = 0; r < 4; ++r) {
            const float inv = 1.0f / l_run[mf][r];
            const int token = b * S_LEN + q0 + wid * 32 + mf * 16 + fg * 4 + r;
            #pragma unroll
            for (int nf = 0; nf < 4; ++nf) {
                const int feat = h * 64 + nf * 16 + fr;
                Oout[(size_t)token * DM + feat] = f2bf(oacc[mf][nf][r] * inv);
            }
        }
    }
}

// ---------------------------------------------------------------------------
extern "C" void kernel_launch(void* const* d_in, const int* in_sizes, int n_in,
                              void* d_out, int out_size, void* d_ws, size_t ws_size,
                              hipStream_t stream)
{
    (void)in_sizes; (void)n_in; (void)out_size; (void)ws_size;
    const float* q  = (const float*)d_in[0];
    const float* k  = (const float*)d_in[1];
    const float* v  = (const float*)d_in[2];
    const float* Wq = (const float*)d_in[3];
    const float* bq = (const float*)d_in[4];
    const float* Wk = (const float*)d_in[5];
    const float* bk = (const float*)d_in[6];
    const float* Wv = (const float*)d_in[7];
    const float* bv = (const float*)d_in[8];
    const float* Wo = (const float*)d_in[9];
    const float* bo = (const float*)d_in[10];

    char* ws = (char*)d_ws;
    const size_t MB = 1024 * 1024;
    unsigned short* Xq  = (unsigned short*)(ws + 0 * MB);   // 8 MiB, later reused as attn-out
    unsigned short* Xk  = (unsigned short*)(ws + 8 * MB);   // 8 MiB
    unsigned short* Xv  = (unsigned short*)(ws + 16 * MB);  // 8 MiB
    unsigned short* Qb  = (unsigned short*)(ws + 24 * MB);  // 8 MiB
    unsigned short* Kb  = (unsigned short*)(ws + 32 * MB);  // 8 MiB
    unsigned short* Vt  = (unsigned short*)(ws + 40 * MB);  // 8 MiB
    unsigned short* Wqb = (unsigned short*)(ws + 48 * MB);  // 2 MiB
    unsigned short* Wkb = (unsigned short*)(ws + 50 * MB);  // 2 MiB
    unsigned short* Wvb = (unsigned short*)(ws + 52 * MB);  // 2 MiB
    unsigned short* Wob = (unsigned short*)(ws + 54 * MB);  // 2 MiB
    unsigned short* AO  = Xq;  // attn output aliases Xq (free after Q-projection)

    CvtArgs ca;
    ca.src[0] = q;  ca.dst[0] = Xq;  ca.n8[0] = (NB * S_LEN * DM) / 8;
    ca.src[1] = k;  ca.dst[1] = Xk;  ca.n8[1] = (NB * S_LEN * DM) / 8;
    ca.src[2] = v;  ca.dst[2] = Xv;  ca.n8[2] = (NB * S_LEN * DM) / 8;
    ca.src[3] = Wq; ca.dst[3] = Wqb; ca.n8[3] = (DM * DM) / 8;
    ca.src[4] = Wk; ca.dst[4] = Wkb; ca.n8[4] = (DM * DM) / 8;
    ca.src[5] = Wv; ca.dst[5] = Wvb; ca.n8[5] = (DM * DM) / 8;
    ca.src[6] = Wo; ca.dst[6] = Wob; ca.n8[6] = (DM * DM) / 8;
    cvt_f32_bf16<<<dim3(1024, 7), 256, 0, stream>>>(ca);

    gemm_qkv<<<dim3(DM / 128, (NB * S_LEN) / 128, 3), 256, 0, stream>>>(
        Xq, Xk, Xv, Wqb, Wkb, Wvb, bq, bk, bv, Qb, Kb, Vt);

    attn_kernel<<<dim3(S_LEN / 128, NB * NH), 256, 0, stream>>>(Qb, Kb, Vt, AO);

    gemm_out<<<dim3(DM / 128, (NB * S_LEN) / 64), 256, 0, stream>>>(
        AO, Wob, bo, (float*)d_out);
}

// Round 13
// 115.308 us; speedup vs baseline: 1.0444x; 1.0444x over previous
//
#include <hip/hip_runtime.h>
#include <stdint.h>

#define S_LEN 2048
#define NB 2
#define NH 16
#define DK 64
#define DM 1024
#define QK_SCALE 0.125f
#define NEG_BIG -1e30f

typedef __attribute__((ext_vector_type(8))) short bf16x8;
typedef __attribute__((ext_vector_type(4))) float f32x4;

static __device__ __forceinline__ f32x4 mfma16(bf16x8 a, bf16x8 b, f32x4 c) {
    return __builtin_amdgcn_mfma_f32_16x16x32_bf16(a, b, c, 0, 0, 0);
}

// async global->LDS, 16B per lane; dst is wave-uniform base, HW adds lane*16
static __device__ __forceinline__ void gload_lds16(const void* g, void* l) {
    __builtin_amdgcn_global_load_lds((const __attribute__((address_space(1))) void*)g,
                                     (__attribute__((address_space(3))) void*)l,
                                     16, 0, 0);
}

// fp32 -> bf16 bits, RNE (inputs always finite here)
static __device__ __forceinline__ unsigned short f2bf(float x) {
    unsigned int u = __float_as_uint(x);
    u += 0x7fffu + ((u >> 16) & 1u);
    return (unsigned short)(u >> 16);
}

// ---------------- conversion: fp32 -> bf16, 7 tensors in one launch -------
struct CvtArgs {
    const float* src[7];
    unsigned short* dst[7];
    int n8[7];
};

__global__ __launch_bounds__(256) void cvt_f32_bf16(CvtArgs a) {
    const int t = blockIdx.y;
    const float* __restrict__ src = a.src[t];
    unsigned short* __restrict__ dst = a.dst[t];
    const int n8 = a.n8[t];
    const int stride = gridDim.x * blockDim.x;
    for (int i = blockIdx.x * blockDim.x + threadIdx.x; i < n8; i += stride) {
        float4 v0 = ((const float4*)src)[(size_t)i * 2];
        float4 v1 = ((const float4*)src)[(size_t)i * 2 + 1];
        union { bf16x8 v; unsigned short h[8]; } u;
        u.h[0] = f2bf(v0.x); u.h[1] = f2bf(v0.y); u.h[2] = f2bf(v0.z); u.h[3] = f2bf(v0.w);
        u.h[4] = f2bf(v1.x); u.h[5] = f2bf(v1.y); u.h[6] = f2bf(v1.z); u.h[7] = f2bf(v1.w);
        ((bf16x8*)dst)[i] = u.v;
    }
}

// ---------------- GEMM core: C[128x128] = A[M,K] * W[N,K]^T ----------------
// m97-structure: 128^2 tile, BK=64, global_load_lds(16B), 2 barriers/K-step,
// T2 swizzle (r7, PMC-verified conflict-free: 9.4M -> 0). r9 known-good form.
static __device__ __forceinline__ void gemm_core_128(
    const unsigned short* __restrict__ A,
    const unsigned short* __restrict__ W,
    unsigned short* sA, unsigned short* sB,
    int K, int m0, int n0, f32x4 acc[4][4])
{
    const int tid = threadIdx.x;
    const int wid = tid >> 6, lane = tid & 63;
    const int wr = wid >> 1, wc = wid & 1;
    const int fr = lane & 15, fg = lane >> 4;
    const int ldr = lane >> 3;
    const int ldc = ((lane & 7) ^ (lane >> 3)) * 8;   // pre-swizzled global src

    const unsigned short* pA = A + (size_t)(m0 + ldr) * K + ldc;
    const unsigned short* pW = W + (size_t)(n0 + ldr) * K + ldc;

    const int cka0 = ((0 + fg) ^ (fr & 7)) * 8;   // swizzled frag-read offsets
    const int cka1 = ((4 + fg) ^ (fr & 7)) * 8;

    for (int k0 = 0; k0 < K; k0 += 64) {
        __syncthreads();  // previous compute done reading LDS
        #pragma unroll
        for (int it = 0; it < 4; ++it) {
            const int rb = wid * 32 + it * 8;
            gload_lds16(pA + (size_t)(rb)*K + k0, sA + rb * 64);
            gload_lds16(pW + (size_t)(rb)*K + k0, sB + rb * 64);
        }
        __syncthreads();  // implies s_waitcnt vmcnt(0): staged data visible
        #pragma unroll
        for (int kf = 0; kf < 2; ++kf) {
            const int cka = kf ? cka1 : cka0;
            bf16x8 af[4], bfr[4];
            #pragma unroll
            for (int mf = 0; mf < 4; ++mf)
                af[mf] = *(const bf16x8*)(sA + (wr * 64 + mf * 16 + fr) * 64 + cka);
            #pragma unroll
            for (int nf = 0; nf < 4; ++nf)
                bfr[nf] = *(const bf16x8*)(sB + (wc * 64 + nf * 16 + fr) * 64 + cka);
            #pragma unroll
            for (int mf = 0; mf < 4; ++mf)
                #pragma unroll
                for (int nf = 0; nf < 4; ++nf)
                    acc[mf][nf] = mfma16(af[mf], bfr[nf], acc[mf][nf]);
        }
    }
}

// ---------------- merged QKV projection (grid.z selects Q/K/V) -------------
// z=0: Q*SCALE -> [B,H,S,dk]  (QK_SCALE=2^-3 folded: bit-exact exponent shift);
// z=1: K -> [B,H,S,dk]; z=2: V -> [B,H,dk,S] (transposed). r9 known-good form.
__global__ __launch_bounds__(256, 3) void gemm_qkv(
    const unsigned short* __restrict__ Xq, const unsigned short* __restrict__ Xk,
    const unsigned short* __restrict__ Xv,
    const unsigned short* __restrict__ Wq, const unsigned short* __restrict__ Wk,
    const unsigned short* __restrict__ Wv,
    const float* __restrict__ bq, const float* __restrict__ bk, const float* __restrict__ bv,
    unsigned short* __restrict__ Qo, unsigned short* __restrict__ Ko,
    unsigned short* __restrict__ Vt)
{
    __shared__ unsigned short sA[128 * 64];
    __shared__ unsigned short sB[128 * 64];
    const int z = blockIdx.z;
    const unsigned short* A = (z == 0) ? Xq : ((z == 1) ? Xk : Xv);
    const unsigned short* W = (z == 0) ? Wq : ((z == 1) ? Wk : Wv);
    const float* bias = (z == 0) ? bq : ((z == 1) ? bk : bv);
    const int m0 = blockIdx.y * 128, n0 = blockIdx.x * 128;

    f32x4 acc[4][4] = {};
    gemm_core_128(A, W, sA, sB, DM, m0, n0, acc);

    const int tid = threadIdx.x, wid = tid >> 6, lane = tid & 63;
    const int wr = wid >> 1, wc = wid & 1, fr = lane & 15, fg = lane >> 4;
    const float sc = (z == 0) ? QK_SCALE : 1.0f;   // fold scale into Q
    unsigned short* Oh = (z == 0) ? Qo : Ko;
    #pragma unroll
    for (int nf = 0; nf < 4; ++nf) {
        const int col = n0 + wc * 64 + nf * 16 + fr;
        const float bb = bias[col];
        const int h = col >> 6, dd = col & (DK - 1);
        #pragma unroll
        for (int mf = 0; mf < 4; ++mf) {
            #pragma unroll
            for (int r = 0; r < 4; ++r) {
                const int row = m0 + wr * 64 + mf * 16 + fg * 4 + r;
                const int b = row >> 11, s = row & (S_LEN - 1);
                const float val = (acc[mf][nf][r] + bb) * sc;
                if (z < 2)
                    Oh[(((size_t)b * NH + h) * S_LEN + s) * DK + dd] = f2bf(val);
                else
                    Vt[(((size_t)b * NH + h) * DK + dd) * S_LEN + s] = f2bf(val);
            }
        }
    }
}

// ---------------- final output projection: BM=64 tile, fp32 out + bias -----
__global__ __launch_bounds__(256, 3) void gemm_out(
    const unsigned short* __restrict__ A, const unsigned short* __restrict__ W,
    const float* __restrict__ bias, float* __restrict__ out)
{
    __shared__ unsigned short sA[64 * 64];
    __shared__ unsigned short sB[128 * 64];

    const int tid = threadIdx.x;
    const int wid = tid >> 6, lane = tid & 63;
    const int wr = wid >> 1, wc = wid & 1;
    const int fr = lane & 15, fg = lane >> 4;
    const int ldr = lane >> 3;
    const int ldc = ((lane & 7) ^ (lane >> 3)) * 8;
    const int m0 = blockIdx.y * 64, n0 = blockIdx.x * 128;

    const unsigned short* pA = A + (size_t)(m0 + ldr) * DM + ldc;
    const unsigned short* pW = W + (size_t)(n0 + ldr) * DM + ldc;

    const int cka0 = ((0 + fg) ^ (fr & 7)) * 8;
    const int cka1 = ((4 + fg) ^ (fr & 7)) * 8;

    f32x4 acc[2][4] = {};

    for (int k0 = 0; k0 < DM; k0 += 64) {
        __syncthreads();
        #pragma unroll
        for (int it = 0; it < 2; ++it) {
            const int rb = wid * 16 + it * 8;
            gload_lds16(pA + (size_t)rb * DM + k0, sA + rb * 64);
        }
        #pragma unroll
        for (int it = 0; it < 4; ++it) {
            const int rb = wid * 32 + it * 8;
            gload_lds16(pW + (size_t)rb * DM + k0, sB + rb * 64);
        }
        __syncthreads();
        #pragma unroll
        for (int kf = 0; kf < 2; ++kf) {
            const int cka = kf ? cka1 : cka0;
            bf16x8 af[2], bfr[4];
            #pragma unroll
            for (int mf = 0; mf < 2; ++mf)
                af[mf] = *(const bf16x8*)(sA + (wr * 32 + mf * 16 + fr) * 64 + cka);
            #pragma unroll
            for (int nf = 0; nf < 4; ++nf)
                bfr[nf] = *(const bf16x8*)(sB + (wc * 64 + nf * 16 + fr) * 64 + cka);
            #pragma unroll
            for (int mf = 0; mf < 2; ++mf)
                #pragma unroll
                for (int nf = 0; nf < 4; ++nf)
                    acc[mf][nf] = mfma16(af[mf], bfr[nf], acc[mf][nf]);
        }
    }

    #pragma unroll
    for (int nf = 0; nf < 4; ++nf) {
        const int col = n0 + wc * 64 + nf * 16 + fr;
        const float bb = bias[col];
        #pragma unroll
        for (int mf = 0; mf < 2; ++mf) {
            #pragma unroll
            for (int r = 0; r < 4; ++r) {
                const int row = m0 + wr * 32 + mf * 16 + fg * 4 + r;
                out[(size_t)row * DM + col] = acc[mf][nf][r] + bb;
            }
        }
    }
}

// ---------------- banded flash attention, LDS-staged + T2 swizzles ---------
// Staged K/V restored (r12 showed direct-global reads stall: MfmaUtil 4.6%).
// NEW: XOR swizzle on sK, sV (pre-swizzled global source, linear gload dest,
// swizzled frag-read) and sP (swizzled scalar write, swizzled b128 read) —
// removes the 16-way conflicts (r12 PMC: 2.1M/dispatch).
__global__ __launch_bounds__(256, 3) void attn_kernel(
    const unsigned short* __restrict__ Qb,   // [B,H,S,64], pre-scaled
    const unsigned short* __restrict__ Kb,   // [B,H,S,64]
    const unsigned short* __restrict__ Vt,   // [B,H,64,S]
    unsigned short* __restrict__ Oout)       // [B*S, 1024] token-major
{
    __shared__ unsigned short sK[128 * 64];
    __shared__ unsigned short sV[64 * 128];
    __shared__ unsigned short sP[4][32 * 128];

    const int tid = threadIdx.x, wid = tid >> 6, lane = tid & 63;
    const int fr = lane & 15, fg = lane >> 4;
    const int qt = blockIdx.x, bh = blockIdx.y;
    const int q0 = qt * 128;
    const size_t base = (size_t)bh * (S_LEN * DK);

    bf16x8 qf[2][2];
    #pragma unroll
    for (int mf = 0; mf < 2; ++mf)
        #pragma unroll
        for (int kf = 0; kf < 2; ++kf)
            qf[mf][kf] = *(const bf16x8*)(Qb + base +
                (size_t)(q0 + wid * 32 + mf * 16 + fr) * DK + kf * 32 + fg * 8);

    f32x4 oacc[2][4] = {};
    float m_run[2][4], l_run[2][4];
    #pragma unroll
    for (int mf = 0; mf < 2; ++mf)
        #pragma unroll
        for (int r = 0; r < 4; ++r) { m_run[mf][r] = NEG_BIG; l_run[mf][r] = 0.f; }

    const int t_lo = (qt == 0) ? 1 : 0;
    const int t_hi = (qt == (S_LEN / 128 - 1)) ? 1 : 2;

    // swizzled source offsets (wave-invariant parts precomputed)
    const int ksrc = (lane >> 3) * 64 + ((lane & 7) ^ (lane >> 3)) * 8;  // sK: 8 rows x 8 chunks
    const int ckr8 = (fr & 7);   // row&7 for 8-chunk reads

    for (int t = t_lo; t <= t_hi; ++t) {
        const int kt0 = q0 + (t - 1) * 128;
        __syncthreads();
        {
            // K tile: 16 gloads of 8 rows x 64 cols; source chunk ^= row&7
            const unsigned short* gK = Kb + base + (size_t)kt0 * DK;
            #pragma unroll
            for (int it = 0; it < 4; ++it) {
                const int chunk = wid * 4 + it;
                gload_lds16(gK + chunk * 512 + ksrc, sK + chunk * 512);
            }
            // V tile: 16 gloads of 4 d-rows x 128 cols; source col-chunk ^= d&15
            const unsigned short* gV = Vt + base + kt0;
            #pragma unroll
            for (int it = 0; it < 4; ++it) {
                const int chunk = wid * 4 + it;
                const int drow = chunk * 4 + fg;
                const int vcol = (fr ^ (drow & 15)) * 8;
                gload_lds16(gV + (size_t)drow * S_LEN + vcol, sV + chunk * 512);
            }
        }
        __syncthreads();

        // S = Q K^T; kfr chunk = (kf*4+fg) ^ (row&7), row&7 == fr&7
        f32x4 sacc[2][8] = {};
        #pragma unroll
        for (int kf = 0; kf < 2; ++kf) {
            const int ck = ((kf * 4 + fg) ^ ckr8) * 8;
            bf16x8 kfr[8];
            #pragma unroll
            for (int nf = 0; nf < 8; ++nf)
                kfr[nf] = *(const bf16x8*)(sK + (nf * 16 + fr) * 64 + ck);
            #pragma unroll
            for (int mf = 0; mf < 2; ++mf)
                #pragma unroll
                for (int nf = 0; nf < 8; ++nf)
                    sacc[mf][nf] = mfma16(qf[mf][kf], kfr[nf], sacc[mf][nf]);
        }

        const int dt = (t - 1) * 128;
        #pragma unroll
        for (int mf = 0; mf < 2; ++mf) {
            #pragma unroll
            for (int r = 0; r < 4; ++r) {
                const int row = wid * 32 + mf * 16 + fg * 4 + r;
                float mm = NEG_BIG;
                #pragma unroll
                for (int nf = 0; nf < 8; ++nf) {
                    const int col = nf * 16 + fr;
                    const int diff = dt + col - row;   // j - i
                    float s = sacc[mf][nf][r];         // pre-scaled via Q
                    s = (diff >= -128 && diff < 128) ? s : NEG_BIG;
                    sacc[mf][nf][r] = s;
                    mm = fmaxf(mm, s);
                }
                #pragma unroll
                for (int d = 1; d < 16; d <<= 1) mm = fmaxf(mm, __shfl_xor(mm, d));
                const float mold = m_run[mf][r];
                const float mn = fmaxf(mold, mm);
                m_run[mf][r] = mn;
                const float alpha = __expf(mold - mn);
                float ps = 0.f;
                const int prow = mf * 16 + fg * 4 + r;       // P row (within wave tile)
                const int psw = (fg * 4 + r) & 7;            // row&7 for write swizzle
                #pragma unroll
                for (int nf = 0; nf < 8; ++nf) {
                    const float p = __expf(sacc[mf][nf][r] - mn);
                    ps += p;
                    const int wch = (nf * 2 + (fr >> 3)) ^ psw;   // swizzled chunk
                    sP[wid][prow * 128 + wch * 8 + (fr & 7)] = f2bf(p);
                }
                #pragma unroll
                for (int d = 1; d < 16; d <<= 1) ps += __shfl_xor(ps, d);
                l_run[mf][r] = l_run[mf][r] * alpha + ps;
                #pragma unroll
                for (int nf = 0; nf < 4; ++nf)
                    oacc[mf][nf][r] = oacc[mf][nf][r] * alpha;
            }
        }

        // O += P @ V; pa chunk = (kf*4+fg)^(fr&7) [16 chunks row], vb chunk = (kf*4+fg)^fr
        #pragma unroll
        for (int kf = 0; kf < 4; ++kf) {
            const int pck = ((kf * 4 + fg) ^ ckr8) * 8;
            const int vck = ((kf * 4 + fg) ^ fr) * 8;
            bf16x8 pa[2], vb[4];
            #pragma unroll
            for (int mf = 0; mf < 2; ++mf)
                pa[mf] = *(const bf16x8*)(&sP[wid][(mf * 16 + fr) * 128 + pck]);
            #pragma unroll
            for (int nf = 0; nf < 4; ++nf)
                vb[nf] = *(const bf16x8*)(sV + (nf * 16 + fr) * 128 + vck);
            #pragma unroll
            for (int mf = 0; mf < 2; ++mf)
                #pragma unroll
                for (int nf = 0; nf < 4; ++nf)
                    oacc[mf][nf] = mfma16(pa[mf], vb[nf], oacc[mf][nf]);
        }
    }

    const int b = bh >> 4, h = bh & 15;
    #pragma unroll
    for (int mf = 0; mf < 2; ++mf) {
        #pragma unroll
        for (int r = 0; r < 4; ++r) {
            const float inv = 1.0f / l_run[mf][r];
            const int token = b * S_LEN + q0 + wid * 32 + mf * 16 + fg * 4 + r;
            #pragma unroll
            for (int nf = 0; nf < 4; ++nf) {
                const int feat = h * 64 + nf * 16 + fr;
                Oout[(size_t)token * DM + feat] = f2bf(oacc[mf][nf][r] * inv);
            }
        }
    }
}

// ---------------------------------------------------------------------------
extern "C" void kernel_launch(void* const* d_in, const int* in_sizes, int n_in,
                              void* d_out, int out_size, void* d_ws, size_t ws_size,
                              hipStream_t stream)
{
    (void)in_sizes; (void)n_in; (void)out_size; (void)ws_size;
    const float* q  = (const float*)d_in[0];
    const float* k  = (const float*)d_in[1];
    const float* v  = (const float*)d_in[2];
    const float* Wq = (const float*)d_in[3];
    const float* bq = (const float*)d_in[4];
    const float* Wk = (const float*)d_in[5];
    const float* bk = (const float*)d_in[6];
    const float* Wv = (const float*)d_in[7];
    const float* bv = (const float*)d_in[8];
    const float* Wo = (const float*)d_in[9];
    const float* bo = (const float*)d_in[10];

    char* ws = (char*)d_ws;
    const size_t MB = 1024 * 1024;
    unsigned short* Xq  = (unsigned short*)(ws + 0 * MB);   // 8 MiB, later reused as attn-out
    unsigned short* Xk  = (unsigned short*)(ws + 8 * MB);   // 8 MiB
    unsigned short* Xv  = (unsigned short*)(ws + 16 * MB);  // 8 MiB
    unsigned short* Qb  = (unsigned short*)(ws + 24 * MB);  // 8 MiB
    unsigned short* Kb  = (unsigned short*)(ws + 32 * MB);  // 8 MiB
    unsigned short* Vt  = (unsigned short*)(ws + 40 * MB);  // 8 MiB
    unsigned short* Wqb = (unsigned short*)(ws + 48 * MB);  // 2 MiB
    unsigned short* Wkb = (unsigned short*)(ws + 50 * MB);  // 2 MiB
    unsigned short* Wvb = (unsigned short*)(ws + 52 * MB);  // 2 MiB
    unsigned short* Wob = (unsigned short*)(ws + 54 * MB);  // 2 MiB
    unsigned short* AO  = Xq;  // attn output aliases Xq (free after Q-projection)

    CvtArgs ca;
    ca.src[0] = q;  ca.dst[0] = Xq;  ca.n8[0] = (NB * S_LEN * DM) / 8;
    ca.src[1] = k;  ca.dst[1] = Xk;  ca.n8[1] = (NB * S_LEN * DM) / 8;
    ca.src[2] = v;  ca.dst[2] = Xv;  ca.n8[2] = (NB * S_LEN * DM) / 8;
    ca.src[3] = Wq; ca.dst[3] = Wqb; ca.n8[3] = (DM * DM) / 8;
    ca.src[4] = Wk; ca.dst[4] = Wkb; ca.n8[4] = (DM * DM) / 8;
    ca.src[5] = Wv; ca.dst[5] = Wvb; ca.n8[5] = (DM * DM) / 8;
    ca.src[6] = Wo; ca.dst[6] = Wob; ca.n8[6] = (DM * DM) / 8;
    cvt_f32_bf16<<<dim3(1024, 7), 256, 0, stream>>>(ca);

    gemm_qkv<<<dim3(DM / 128, (NB * S_LEN) / 128, 3), 256, 0, stream>>>(
        Xq, Xk, Xv, Wqb, Wkb, Wvb, bq, bk, bv, Qb, Kb, Vt);

    attn_kernel<<<dim3(S_LEN / 128, NB * NH), 256, 0, stream>>>(Qb, Kb, Vt, AO);

    gemm_out<<<dim3(DM / 128, (NB * S_LEN) / 64), 256, 0, stream>>>(
        AO, Wob, bo, (float*)d_out);
}

// Round 14
// 102.040 us; speedup vs baseline: 1.1802x; 1.1300x over previous
//
#include <hip/hip_runtime.h>
#include <stdint.h>

#define S_LEN 2048
#define NB 2
#define NH 16
#define DK 64
#define DM 1024
#define QK_SCALE 0.125f
#define NEG_BIG -1e30f

typedef __attribute__((ext_vector_type(8))) short bf16x8;
typedef __attribute__((ext_vector_type(4))) float f32x4;

static __device__ __forceinline__ f32x4 mfma16(bf16x8 a, bf16x8 b, f32x4 c) {
    return __builtin_amdgcn_mfma_f32_16x16x32_bf16(a, b, c, 0, 0, 0);
}

// async global->LDS, 16B per lane; dst is wave-uniform base, HW adds lane*16
static __device__ __forceinline__ void gload_lds16(const void* g, void* l) {
    __builtin_amdgcn_global_load_lds((const __attribute__((address_space(1))) void*)g,
                                     (__attribute__((address_space(3))) void*)l,
                                     16, 0, 0);
}

// fp32 -> bf16 bits, RNE (inputs always finite here)
static __device__ __forceinline__ unsigned short f2bf(float x) {
    unsigned int u = __float_as_uint(x);
    u += 0x7fffu + ((u >> 16) & 1u);
    return (unsigned short)(u >> 16);
}

// ---------------- conversion: fp32 -> bf16, 7 tensors in one launch -------
struct CvtArgs {
    const float* src[7];
    unsigned short* dst[7];
    int n8[7];
};

__global__ __launch_bounds__(256) void cvt_f32_bf16(CvtArgs a) {
    const int t = blockIdx.y;
    const float* __restrict__ src = a.src[t];
    unsigned short* __restrict__ dst = a.dst[t];
    const int n8 = a.n8[t];
    const int stride = gridDim.x * blockDim.x;
    for (int i = blockIdx.x * blockDim.x + threadIdx.x; i < n8; i += stride) {
        float4 v0 = ((const float4*)src)[(size_t)i * 2];
        float4 v1 = ((const float4*)src)[(size_t)i * 2 + 1];
        union { bf16x8 v; unsigned short h[8]; } u;
        u.h[0] = f2bf(v0.x); u.h[1] = f2bf(v0.y); u.h[2] = f2bf(v0.z); u.h[3] = f2bf(v0.w);
        u.h[4] = f2bf(v1.x); u.h[5] = f2bf(v1.y); u.h[6] = f2bf(v1.z); u.h[7] = f2bf(v1.w);
        ((bf16x8*)dst)[i] = u.v;
    }
}

// ---------------- GEMM core: C[128x128] = A[M,K] * W[N,K]^T ----------------
// m97-structure: 128^2 tile, BK=64, global_load_lds(16B), 2 barriers/K-step,
// T2 swizzle (r7, PMC-verified conflict-free: 9.4M -> 0). r9 known-good form.
static __device__ __forceinline__ void gemm_core_128(
    const unsigned short* __restrict__ A,
    const unsigned short* __restrict__ W,
    unsigned short* sA, unsigned short* sB,
    int K, int m0, int n0, f32x4 acc[4][4])
{
    const int tid = threadIdx.x;
    const int wid = tid >> 6, lane = tid & 63;
    const int wr = wid >> 1, wc = wid & 1;
    const int fr = lane & 15, fg = lane >> 4;
    const int ldr = lane >> 3;
    const int ldc = ((lane & 7) ^ (lane >> 3)) * 8;   // pre-swizzled global src

    const unsigned short* pA = A + (size_t)(m0 + ldr) * K + ldc;
    const unsigned short* pW = W + (size_t)(n0 + ldr) * K + ldc;

    const int cka0 = ((0 + fg) ^ (fr & 7)) * 8;   // swizzled frag-read offsets
    const int cka1 = ((4 + fg) ^ (fr & 7)) * 8;

    for (int k0 = 0; k0 < K; k0 += 64) {
        __syncthreads();  // previous compute done reading LDS
        #pragma unroll
        for (int it = 0; it < 4; ++it) {
            const int rb = wid * 32 + it * 8;
            gload_lds16(pA + (size_t)(rb)*K + k0, sA + rb * 64);
            gload_lds16(pW + (size_t)(rb)*K + k0, sB + rb * 64);
        }
        __syncthreads();  // implies s_waitcnt vmcnt(0): staged data visible
        #pragma unroll
        for (int kf = 0; kf < 2; ++kf) {
            const int cka = kf ? cka1 : cka0;
            bf16x8 af[4], bfr[4];
            #pragma unroll
            for (int mf = 0; mf < 4; ++mf)
                af[mf] = *(const bf16x8*)(sA + (wr * 64 + mf * 16 + fr) * 64 + cka);
            #pragma unroll
            for (int nf = 0; nf < 4; ++nf)
                bfr[nf] = *(const bf16x8*)(sB + (wc * 64 + nf * 16 + fr) * 64 + cka);
            #pragma unroll
            for (int mf = 0; mf < 4; ++mf)
                #pragma unroll
                for (int nf = 0; nf < 4; ++nf)
                    acc[mf][nf] = mfma16(af[mf], bfr[nf], acc[mf][nf]);
        }
    }
}

// ---------------- merged QKV projection (grid.z selects Q/K/V) -------------
// z=0: Q*SCALE -> [B,H,S,dk]  (QK_SCALE=2^-3 folded: bit-exact exponent shift);
// z=1: K -> [B,H,S,dk];
// z=2: V -> [B,H,dk,S] via LDS transpose (NEW): the old per-lane 2B scatter
//      (each lane a different Vt row, 4KB apart; 1024 scattered stores/block,
//      partial-line RMW -> WRITE_SIZE 40MB vs 24MB ideal) is replaced by an
//      LDS-transposed epilogue with coalesced 16B stores (4 lanes per 64B line).
__global__ __launch_bounds__(256, 3) void gemm_qkv(
    const unsigned short* __restrict__ Xq, const unsigned short* __restrict__ Xk,
    const unsigned short* __restrict__ Xv,
    const unsigned short* __restrict__ Wq, const unsigned short* __restrict__ Wk,
    const unsigned short* __restrict__ Wv,
    const float* __restrict__ bq, const float* __restrict__ bk, const float* __restrict__ bv,
    unsigned short* __restrict__ Qo, unsigned short* __restrict__ Ko,
    unsigned short* __restrict__ Vt)
{
    __shared__ unsigned short sbuf[2 * 128 * 64];   // 32KB: [A 16KB][B 16KB]; reused as 128x128 for z==2
    unsigned short* sA = sbuf;
    unsigned short* sB = sbuf + 128 * 64;

    const int z = blockIdx.z;
    const unsigned short* A = (z == 0) ? Xq : ((z == 1) ? Xk : Xv);
    const unsigned short* W = (z == 0) ? Wq : ((z == 1) ? Wk : Wv);
    const float* bias = (z == 0) ? bq : ((z == 1) ? bk : bv);
    const int m0 = blockIdx.y * 128, n0 = blockIdx.x * 128;

    f32x4 acc[4][4] = {};
    gemm_core_128(A, W, sA, sB, DM, m0, n0, acc);

    const int tid = threadIdx.x, wid = tid >> 6, lane = tid & 63;
    const int wr = wid >> 1, wc = wid & 1, fr = lane & 15, fg = lane >> 4;

    if (z < 2) {
        const float sc = (z == 0) ? QK_SCALE : 1.0f;   // fold scale into Q
        unsigned short* Oh = (z == 0) ? Qo : Ko;
        #pragma unroll
        for (int nf = 0; nf < 4; ++nf) {
            const int col = n0 + wc * 64 + nf * 16 + fr;
            const float bb = bias[col];
            const int h = col >> 6, dd = col & (DK - 1);
            #pragma unroll
            for (int mf = 0; mf < 4; ++mf) {
                #pragma unroll
                for (int r = 0; r < 4; ++r) {
                    const int row = m0 + wr * 64 + mf * 16 + fg * 4 + r;
                    const int b = row >> 11, s = row & (S_LEN - 1);
                    Oh[(((size_t)b * NH + h) * S_LEN + s) * DK + dd] =
                        f2bf((acc[mf][nf][r] + bb) * sc);
                }
            }
        }
    } else {
        // ---- V^T epilogue: transpose through LDS, then coalesced stores ----
        __syncthreads();   // all waves done reading sA/sB
        // scatter: logical [c][row] stored at [c][row ^ 8*(c&15)] (bank spread)
        #pragma unroll
        for (int nf = 0; nf < 4; ++nf) {
            const int c = wc * 64 + nf * 16 + fr;          // local col 0..127
            const float bb = bias[n0 + c];
            const int sw = (c & 15) * 8;
            #pragma unroll
            for (int mf = 0; mf < 4; ++mf) {
                #pragma unroll
                for (int r = 0; r < 4; ++r) {
                    const int row = wr * 64 + mf * 16 + fg * 4 + r;   // 0..127
                    sbuf[c * 128 + (row ^ sw)] = f2bf(acc[mf][nf][r] + bb);
                }
            }
        }
        __syncthreads();
        const int brow = m0 >> 11;              // batch (m0 multiple of 128)
        const int s_base = m0 & (S_LEN - 1);    // token start, 128-aligned
        #pragma unroll
        for (int pass = 0; pass < 2; ++pass) {
            const int c = pass * 64 + (tid >> 2);           // local col 0..127
            const int colg = n0 + c;
            const int h = colg >> 6, dd = colg & (DK - 1);
            unsigned short* dst = Vt + (((size_t)brow * NH + h) * DK + dd) * S_LEN + s_base;
            const int c15 = c & 15;
            #pragma unroll
            for (int j = 0; j < 4; ++j) {
                const int chunk = (tid & 3) + j * 4;        // 16B chunk of the row
                *(bf16x8*)(dst + chunk * 8) =
                    *(const bf16x8*)(sbuf + c * 128 + ((chunk ^ c15) * 8));
            }
        }
    }
}

// ---------------- final output projection: BM=64 tile, fp32 out + bias -----
__global__ __launch_bounds__(256, 2) void gemm_out(
    const unsigned short* __restrict__ A, const unsigned short* __restrict__ W,
    const float* __restrict__ bias, float* __restrict__ out)
{
    __shared__ unsigned short sA[64 * 64];
    __shared__ unsigned short sB[128 * 64];

    const int tid = threadIdx.x;
    const int wid = tid >> 6, lane = tid & 63;
    const int wr = wid >> 1, wc = wid & 1;
    const int fr = lane & 15, fg = lane >> 4;
    const int ldr = lane >> 3;
    const int ldc = ((lane & 7) ^ (lane >> 3)) * 8;
    const int m0 = blockIdx.y * 64, n0 = blockIdx.x * 128;

    const unsigned short* pA = A + (size_t)(m0 + ldr) * DM + ldc;
    const unsigned short* pW = W + (size_t)(n0 + ldr) * DM + ldc;

    const int cka0 = ((0 + fg) ^ (fr & 7)) * 8;
    const int cka1 = ((4 + fg) ^ (fr & 7)) * 8;

    f32x4 acc[2][4] = {};

    for (int k0 = 0; k0 < DM; k0 += 64) {
        __syncthreads();
        #pragma unroll
        for (int it = 0; it < 2; ++it) {
            const int rb = wid * 16 + it * 8;
            gload_lds16(pA + (size_t)rb * DM + k0, sA + rb * 64);
        }
        #pragma unroll
        for (int it = 0; it < 4; ++it) {
            const int rb = wid * 32 + it * 8;
            gload_lds16(pW + (size_t)rb * DM + k0, sB + rb * 64);
        }
        __syncthreads();
        #pragma unroll
        for (int kf = 0; kf < 2; ++kf) {
            const int cka = kf ? cka1 : cka0;
            bf16x8 af[2], bfr[4];
            #pragma unroll
            for (int mf = 0; mf < 2; ++mf)
                af[mf] = *(const bf16x8*)(sA + (wr * 32 + mf * 16 + fr) * 64 + cka);
            #pragma unroll
            for (int nf = 0; nf < 4; ++nf)
                bfr[nf] = *(const bf16x8*)(sB + (wc * 64 + nf * 16 + fr) * 64 + cka);
            #pragma unroll
            for (int mf = 0; mf < 2; ++mf)
                #pragma unroll
                for (int nf = 0; nf < 4; ++nf)
                    acc[mf][nf] = mfma16(af[mf], bfr[nf], acc[mf][nf]);
        }
    }

    #pragma unroll
    for (int nf = 0; nf < 4; ++nf) {
        const int col = n0 + wc * 64 + nf * 16 + fr;
        const float bb = bias[col];
        #pragma unroll
        for (int mf = 0; mf < 2; ++mf) {
            #pragma unroll
            for (int r = 0; r < 4; ++r) {
                const int row = m0 + wr * 32 + mf * 16 + fg * 4 + r;
                out[(size_t)row * DM + col] = acc[mf][nf][r] + bb;
            }
        }
    }
}

// ---------------- banded flash attention (r10 measured-best form) ----------
// Q is pre-scaled by QK_SCALE (folded into gemm_qkv) -> no scale mul here.
__global__ __launch_bounds__(256, 2) void attn_kernel(
    const unsigned short* __restrict__ Qb,   // [B,H,S,64], pre-scaled
    const unsigned short* __restrict__ Kb,   // [B,H,S,64]
    const unsigned short* __restrict__ Vt,   // [B,H,64,S]
    unsigned short* __restrict__ Oout)       // [B*S, 1024] token-major
{
    __shared__ unsigned short sK[128 * 64];
    __shared__ unsigned short sV[64 * 128];
    __shared__ unsigned short sP[4][32 * 128];

    const int tid = threadIdx.x, wid = tid >> 6, lane = tid & 63;
    const int fr = lane & 15, fg = lane >> 4;
    const int qt = blockIdx.x, bh = blockIdx.y;
    const int q0 = qt * 128;
    const size_t base = (size_t)bh * (S_LEN * DK);

    bf16x8 qf[2][2];
    #pragma unroll
    for (int mf = 0; mf < 2; ++mf)
        #pragma unroll
        for (int kf = 0; kf < 2; ++kf)
            qf[mf][kf] = *(const bf16x8*)(Qb + base +
                (size_t)(q0 + wid * 32 + mf * 16 + fr) * DK + kf * 32 + fg * 8);

    f32x4 oacc[2][4] = {};
    float m_run[2][4], l_run[2][4];
    #pragma unroll
    for (int mf = 0; mf < 2; ++mf)
        #pragma unroll
        for (int r = 0; r < 4; ++r) { m_run[mf][r] = NEG_BIG; l_run[mf][r] = 0.f; }

    const int t_lo = (qt == 0) ? 1 : 0;
    const int t_hi = (qt == (S_LEN / 128 - 1)) ? 1 : 2;

    for (int t = t_lo; t <= t_hi; ++t) {
        const int kt0 = q0 + (t - 1) * 128;
        __syncthreads();
        {
            const unsigned short* gK = Kb + base + (size_t)kt0 * DK;
            #pragma unroll
            for (int it = 0; it < 4; ++it) {
                const int chunk = wid * 4 + it;
                gload_lds16(gK + chunk * 512 + lane * 8, sK + chunk * 512);
            }
            const unsigned short* gV = Vt + base + kt0;
            #pragma unroll
            for (int it = 0; it < 4; ++it) {
                const int chunk = wid * 4 + it;
                gload_lds16(gV + (size_t)(chunk * 4 + fg) * S_LEN + fr * 8, sV + chunk * 512);
            }
        }
        __syncthreads();

        f32x4 sacc[2][8] = {};
        #pragma unroll
        for (int kf = 0; kf < 2; ++kf) {
            bf16x8 kfr[8];
            #pragma unroll
            for (int nf = 0; nf < 8; ++nf)
                kfr[nf] = *(const bf16x8*)(sK + (nf * 16 + fr) * 64 + kf * 32 + fg * 8);
            #pragma unroll
            for (int mf = 0; mf < 2; ++mf)
                #pragma unroll
                for (int nf = 0; nf < 8; ++nf)
                    sacc[mf][nf] = mfma16(qf[mf][kf], kfr[nf], sacc[mf][nf]);
        }

        const int dt = (t - 1) * 128;
        #pragma unroll
        for (int mf = 0; mf < 2; ++mf) {
            #pragma unroll
            for (int r = 0; r < 4; ++r) {
                const int row = wid * 32 + mf * 16 + fg * 4 + r;
                float mm = NEG_BIG;
                #pragma unroll
                for (int nf = 0; nf < 8; ++nf) {
                    const int col = nf * 16 + fr;
                    const int diff = dt + col - row;   // j - i
                    float s = sacc[mf][nf][r];         // pre-scaled via Q
                    s = (diff >= -128 && diff < 128) ? s : NEG_BIG;
                    sacc[mf][nf][r] = s;
                    mm = fmaxf(mm, s);
                }
                #pragma unroll
                for (int d = 1; d < 16; d <<= 1) mm = fmaxf(mm, __shfl_xor(mm, d));
                const float mold = m_run[mf][r];
                const float mn = fmaxf(mold, mm);
                m_run[mf][r] = mn;
                const float alpha = __expf(mold - mn);
                float ps = 0.f;
                #pragma unroll
                for (int nf = 0; nf < 8; ++nf) {
                    const float p = __expf(sacc[mf][nf][r] - mn);
                    ps += p;
                    sP[wid][(mf * 16 + fg * 4 + r) * 128 + nf * 16 + fr] = f2bf(p);
                }
                #pragma unroll
                for (int d = 1; d < 16; d <<= 1) ps += __shfl_xor(ps, d);
                l_run[mf][r] = l_run[mf][r] * alpha + ps;
                #pragma unroll
                for (int nf = 0; nf < 4; ++nf)
                    oacc[mf][nf][r] = oacc[mf][nf][r] * alpha;
            }
        }

        #pragma unroll
        for (int kf = 0; kf < 4; ++kf) {
            bf16x8 pa[2], vb[4];
            #pragma unroll
            for (int mf = 0; mf < 2; ++mf)
                pa[mf] = *(const bf16x8*)(&sP[wid][(mf * 16 + fr) * 128 + kf * 32 + fg * 8]);
            #pragma unroll
            for (int nf = 0; nf < 4; ++nf)
                vb[nf] = *(const bf16x8*)(sV + (nf * 16 + fr) * 128 + kf * 32 + fg * 8);
            #pragma unroll
            for (int mf = 0; mf < 2; ++mf)
                #pragma unroll
                for (int nf = 0; nf < 4; ++nf)
                    oacc[mf][nf] = mfma16(pa[mf], vb[nf], oacc[mf][nf]);
        }
    }

    const int b = bh >> 4, h = bh & 15;
    #pragma unroll
    for (int mf = 0; mf < 2; ++mf) {
        #pragma unroll
        for (int r = 0; r < 4; ++r) {
            const float inv = 1.0f / l_run[mf][r];
            const int token = b * S_LEN + q0 + wid * 32 + mf * 16 + fg * 4 + r;
            #pragma unroll
            for (int nf = 0; nf < 4; ++nf) {
                const int feat = h * 64 + nf * 16 + fr;
                Oout[(size_t)token * DM + feat] = f2bf(oacc[mf][nf][r] * inv);
            }
        }
    }
}

// ---------------------------------------------------------------------------
extern "C" void kernel_launch(void* const* d_in, const int* in_sizes, int n_in,
                              void* d_out, int out_size, void* d_ws, size_t ws_size,
                              hipStream_t stream)
{
    (void)in_sizes; (void)n_in; (void)out_size; (void)ws_size;
    const float* q  = (const float*)d_in[0];
    const float* k  = (const float*)d_in[1];
    const float* v  = (const float*)d_in[2];
    const float* Wq = (const float*)d_in[3];
    const float* bq = (const float*)d_in[4];
    const float* Wk = (const float*)d_in[5];
    const float* bk = (const float*)d_in[6];
    const float* Wv = (const float*)d_in[7];
    const float* bv = (const float*)d_in[8];
    const float* Wo = (const float*)d_in[9];
    const float* bo = (const float*)d_in[10];

    char* ws = (char*)d_ws;
    const size_t MB = 1024 * 1024;
    unsigned short* Xq  = (unsigned short*)(ws + 0 * MB);   // 8 MiB, later reused as attn-out
    unsigned short* Xk  = (unsigned short*)(ws + 8 * MB);   // 8 MiB
    unsigned short* Xv  = (unsigned short*)(ws + 16 * MB);  // 8 MiB
    unsigned short* Qb  = (unsigned short*)(ws + 24 * MB);  // 8 MiB
    unsigned short* Kb  = (unsigned short*)(ws + 32 * MB);  // 8 MiB
    unsigned short* Vt  = (unsigned short*)(ws + 40 * MB);  // 8 MiB
    unsigned short* Wqb = (unsigned short*)(ws + 48 * MB);  // 2 MiB
    unsigned short* Wkb = (unsigned short*)(ws + 50 * MB);  // 2 MiB
    unsigned short* Wvb = (unsigned short*)(ws + 52 * MB);  // 2 MiB
    unsigned short* Wob = (unsigned short*)(ws + 54 * MB);  // 2 MiB
    unsigned short* AO  = Xq;  // attn output aliases Xq (free after Q-projection)

    CvtArgs ca;
    ca.src[0] = q;  ca.dst[0] = Xq;  ca.n8[0] = (NB * S_LEN * DM) / 8;
    ca.src[1] = k;  ca.dst[1] = Xk;  ca.n8[1] = (NB * S_LEN * DM) / 8;
    ca.src[2] = v;  ca.dst[2] = Xv;  ca.n8[2] = (NB * S_LEN * DM) / 8;
    ca.src[3] = Wq; ca.dst[3] = Wqb; ca.n8[3] = (DM * DM) / 8;
    ca.src[4] = Wk; ca.dst[4] = Wkb; ca.n8[4] = (DM * DM) / 8;
    ca.src[5] = Wv; ca.dst[5] = Wvb; ca.n8[5] = (DM * DM) / 8;
    ca.src[6] = Wo; ca.dst[6] = Wob; ca.n8[6] = (DM * DM) / 8;
    cvt_f32_bf16<<<dim3(1024, 7), 256, 0, stream>>>(ca);

    gemm_qkv<<<dim3(DM / 128, (NB * S_LEN) / 128, 3), 256, 0, stream>>>(
        Xq, Xk, Xv, Wqb, Wkb, Wvb, bq, bk, bv, Qb, Kb, Vt);

    attn_kernel<<<dim3(S_LEN / 128, NB * NH), 256, 0, stream>>>(Qb, Kb, Vt, AO);

    gemm_out<<<dim3(DM / 128, (NB * S_LEN) / 64), 256, 0, stream>>>(
        AO, Wob, bo, (float*)d_out);
}